// Round 4
// baseline (1088.461 us; speedup 1.0000x reference)
//
#include <hip/hip_runtime.h>
#include <math.h>

// Problem constants (B,C,T fixed by setup_inputs)
#define BB 4
#define CC 512
#define TT 2048
#define GG 32
#define HEADS 8
#define CPG (CC/GG)        // 16 channels per group
#define GN_N (CPG*TT)      // 32768 elements per group
#define CH 64              // C / HEADS
#define EPS 1e-5f

// ---------------------------------------------------------------------------
// Kernel 1: GroupNorm.  One block per (b, group).  Group = 16 ch x 2048 = 32768
// contiguous floats.  Two-pass (sum/sumsq reduce, then normalize), float4.
// Memory-bound: reads+writes 2 x 16.8 MB => ~6 us at 6 TB/s.
// ---------------------------------------------------------------------------
__global__ __launch_bounds__(256) void gn_kernel(
    const float* __restrict__ x, const float* __restrict__ w,
    const float* __restrict__ bvec, float* __restrict__ h) {
  int bg = blockIdx.x;            // b*GG + g
  int b = bg / GG, g = bg % GG;
  const float* xp = x + ((size_t)b * CC + (size_t)g * CPG) * TT;
  float* hp = h + ((size_t)b * CC + (size_t)g * CPG) * TT;
  int tid = threadIdx.x;

  float s = 0.f, ss = 0.f;
  const float4* x4 = (const float4*)xp;
  for (int i = tid; i < GN_N / 4; i += 256) {
    float4 v = x4[i];
    s  += v.x + v.y + v.z + v.w;
    ss += v.x * v.x + v.y * v.y + v.z * v.z + v.w * v.w;
  }
  // wave64 reduce then cross-wave via LDS
  for (int off = 32; off > 0; off >>= 1) {
    s  += __shfl_down(s, off);
    ss += __shfl_down(ss, off);
  }
  __shared__ float red[2][4];
  __shared__ float mu_s, rstd_s;
  int wid = tid >> 6;
  if ((tid & 63) == 0) { red[0][wid] = s; red[1][wid] = ss; }
  __syncthreads();
  if (tid == 0) {
    float S = 0.f, SS = 0.f;
    for (int i = 0; i < 4; i++) { S += red[0][i]; SS += red[1][i]; }
    float mu  = S / (float)GN_N;
    float var = SS / (float)GN_N - mu * mu;
    mu_s = mu; rstd_s = rsqrtf(var + EPS);
  }
  __syncthreads();
  float mu = mu_s, rstd = rstd_s;
  float4* h4 = (float4*)hp;
  for (int i = tid; i < GN_N / 4; i += 256) {
    int c = g * CPG + (i * 4) / TT;         // float4 never straddles a row (2048%4==0)
    float sw = w[c] * rstd;
    float sb = bvec[c] - mu * sw;
    float4 v = x4[i];
    float4 o;
    o.x = v.x * sw + sb; o.y = v.y * sw + sb;
    o.z = v.z * sw + sb; o.w = v.w * sw + sb;
    h4[i] = o;
  }
}

// ---------------------------------------------------------------------------
// Kernel 2/4: fp32 SGEMM  C[b][m][n] = sum_k A[m][k]*Bm[b][k][n] + bias[m]
//             (+ optional residual) .  K=512, N=T=2048 fixed; M = 1536 or 512.
// 128x128 block tile, BK=16, 256 threads, 8x8 micro-tile.
// Column mapping n = {tx*4, 64+tx*4} so LDS b128 reads are 2-way (free).
// As padded to 132 so the transpose-store is 2-way (free).
// ---------------------------------------------------------------------------
template <bool ADD_RES>
__global__ __launch_bounds__(256) void gemm_kernel(
    const float* __restrict__ A,     // M x 512, row-major
    const float* __restrict__ Bm,    // B x 512 x T
    const float* __restrict__ bias,  // M
    const float* __restrict__ resid, // B x M x T (only when ADD_RES)
    float* __restrict__ Cm,          // B x M x T
    int M) {
  const int K = 512;
  int b  = blockIdx.z;
  int n0 = blockIdx.x * 128;
  int m0 = blockIdx.y * 128;
  const float* Bp = Bm + (size_t)b * K * TT;
  float* Cp = Cm + (size_t)b * M * TT;

  __shared__ float As[16][132];   // [k][m], padded: transpose-store 2-way
  __shared__ float Bs[16][128];   // [k][n]

  int tid = threadIdx.x;
  int tx = tid & 15, ty = tid >> 4;

  float acc[8][8];
#pragma unroll
  for (int i = 0; i < 8; i++)
#pragma unroll
    for (int j = 0; j < 8; j++) acc[i][j] = 0.f;

  int la_m = tid >> 2;            // 0..63
  int la_k = (tid & 3) * 4;       // 0,4,8,12
  int lb_k = tid >> 5;            // 0..7
  int lb_n = (tid & 31) * 4;      // 0..124

  for (int k0 = 0; k0 < K; k0 += 16) {
    float4 a0 = *(const float4*)&A[(size_t)(m0 + la_m) * K + k0 + la_k];
    float4 a1 = *(const float4*)&A[(size_t)(m0 + 64 + la_m) * K + k0 + la_k];
    float4 b0 = *(const float4*)&Bp[(size_t)(k0 + lb_k) * TT + n0 + lb_n];
    float4 b1 = *(const float4*)&Bp[(size_t)(k0 + 8 + lb_k) * TT + n0 + lb_n];
    __syncthreads();              // previous iter's LDS reads done
    As[la_k + 0][la_m] = a0.x; As[la_k + 1][la_m] = a0.y;
    As[la_k + 2][la_m] = a0.z; As[la_k + 3][la_m] = a0.w;
    As[la_k + 0][64 + la_m] = a1.x; As[la_k + 1][64 + la_m] = a1.y;
    As[la_k + 2][64 + la_m] = a1.z; As[la_k + 3][64 + la_m] = a1.w;
    *(float4*)&Bs[lb_k][lb_n] = b0;
    *(float4*)&Bs[lb_k + 8][lb_n] = b1;
    __syncthreads();
#pragma unroll
    for (int k = 0; k < 16; k++) {
      float4 av0 = *(const float4*)&As[k][ty * 4];
      float4 av1 = *(const float4*)&As[k][64 + ty * 4];
      float4 bv0 = *(const float4*)&Bs[k][tx * 4];
      float4 bv1 = *(const float4*)&Bs[k][64 + tx * 4];
      float am[8] = {av0.x, av0.y, av0.z, av0.w, av1.x, av1.y, av1.z, av1.w};
      float bn[8] = {bv0.x, bv0.y, bv0.z, bv0.w, bv1.x, bv1.y, bv1.z, bv1.w};
#pragma unroll
      for (int i = 0; i < 8; i++)
#pragma unroll
        for (int j = 0; j < 8; j++)
          acc[i][j] = fmaf(am[i], bn[j], acc[i][j]);
    }
  }
  // epilogue: bias (+ residual) and store
#pragma unroll
  for (int ih = 0; ih < 2; ih++) {
#pragma unroll
    for (int i = 0; i < 4; i++) {
      int m = m0 + ih * 64 + ty * 4 + i;
      float bb = bias[m];
#pragma unroll
      for (int jh = 0; jh < 2; jh++) {
        int n = n0 + jh * 64 + tx * 4;
        float4 r;
        r.x = acc[ih * 4 + i][jh * 4 + 0] + bb;
        r.y = acc[ih * 4 + i][jh * 4 + 1] + bb;
        r.z = acc[ih * 4 + i][jh * 4 + 2] + bb;
        r.w = acc[ih * 4 + i][jh * 4 + 3] + bb;
        if (ADD_RES) {
          float4 xv = *(const float4*)&resid[(size_t)b * M * TT + (size_t)m * TT + n];
          r.x += xv.x; r.y += xv.y; r.z += xv.z; r.w += xv.w;
        }
        *(float4*)&Cp[(size_t)m * TT + n] = r;
      }
    }
  }
}

// ---------------------------------------------------------------------------
// Kernel 3: fp32 flash attention.  Block = (bh head, 64-query tile), 256 thr.
// qkv layout (B, 3C, T); head hh uses rows hh*192 + {q:0..63, k:64..127,
// v:128..191}.  Q,K staged as [ch][t] (natural layout, contiguous in t),
// V transposed to [s][c] on load, P tile 64x64 in LDS, online softmax.
// acc = 4 queries x 4 channels per thread.
// ---------------------------------------------------------------------------
__global__ __launch_bounds__(256) void attn_kernel(
    const float* __restrict__ qkv,  // B x 1536 x T
    float* __restrict__ aout) {     // B x 512 x T
  int bh = blockIdx.y;              // 0..31
  int b = bh / HEADS, hh = bh % HEADS;
  int qt0 = blockIdx.x * 64;
  const float* qp = qkv + ((size_t)b * 1536 + (size_t)hh * 192) * TT;
  const float* kp = qp + (size_t)64 * TT;
  const float* vp = qp + (size_t)128 * TT;

  __shared__ float Qs[64][65];    // [ch][q]
  __shared__ float Ks[64][65];    // [ch][s]
  __shared__ float VsT[64][65];   // [s][ch]
  __shared__ float Ps[64][65];    // [q][s] scores -> probs; reused for output
  __shared__ float mS[64], lS[64], corrS[64];
  __shared__ float pmax[64][4], psum[64][4];

  int tid = threadIdx.x;
  int tx = tid & 15, ty = tid >> 4;
  const float scale = 0.3535533905932738f;  // 1/sqrt(sqrt(64))

  for (int i = tid; i < 1024; i += 256) {   // 64ch x 16 float4
    int c = i >> 4, q4 = (i & 15) * 4;
    float4 v = *(const float4*)&qp[(size_t)c * TT + qt0 + q4];
    Qs[c][q4 + 0] = v.x * scale; Qs[c][q4 + 1] = v.y * scale;
    Qs[c][q4 + 2] = v.z * scale; Qs[c][q4 + 3] = v.w * scale;
  }
  if (tid < 64) { mS[tid] = -INFINITY; lS[tid] = 0.f; }
  float acc[4][4];
#pragma unroll
  for (int i = 0; i < 4; i++)
#pragma unroll
    for (int j = 0; j < 4; j++) acc[i][j] = 0.f;
  __syncthreads();

  for (int s0 = 0; s0 < TT; s0 += 64) {
    // stage K (scaled, [ch][s]) and V (transposed, [s][ch])
    for (int i = tid; i < 1024; i += 256) {
      int c = i >> 4, s4 = (i & 15) * 4;
      float4 kv = *(const float4*)&kp[(size_t)c * TT + s0 + s4];
      Ks[c][s4 + 0] = kv.x * scale; Ks[c][s4 + 1] = kv.y * scale;
      Ks[c][s4 + 2] = kv.z * scale; Ks[c][s4 + 3] = kv.w * scale;
      float4 vv = *(const float4*)&vp[(size_t)c * TT + s0 + s4];
      VsT[s4 + 0][c] = vv.x; VsT[s4 + 1][c] = vv.y;
      VsT[s4 + 2][c] = vv.z; VsT[s4 + 3][c] = vv.w;   // 2-way, free
    }
    __syncthreads();

    // scores: thread -> S[q=ty*4..+3][s=tx*4..+3]
    float sc[4][4];
#pragma unroll
    for (int i = 0; i < 4; i++)
#pragma unroll
      for (int j = 0; j < 4; j++) sc[i][j] = 0.f;
    for (int c = 0; c < 64; c++) {
      float4 qv = *(const float4*)&Qs[c][ty * 4];   // broadcast
      float4 kv = *(const float4*)&Ks[c][tx * 4];   // 2-way, free
      float qa[4] = {qv.x, qv.y, qv.z, qv.w};
      float ka[4] = {kv.x, kv.y, kv.z, kv.w};
#pragma unroll
      for (int i = 0; i < 4; i++)
#pragma unroll
        for (int j = 0; j < 4; j++)
          sc[i][j] = fmaf(qa[i], ka[j], sc[i][j]);
    }
#pragma unroll
    for (int i = 0; i < 4; i++)
      *(float4*)&Ps[ty * 4 + i][tx * 4] =
          make_float4(sc[i][0], sc[i][1], sc[i][2], sc[i][3]);
    __syncthreads();

    // online softmax: 4 threads per row
    int r = tid >> 2, seg = tid & 3;
    float pm = -INFINITY;
    for (int j = 0; j < 16; j++) pm = fmaxf(pm, Ps[r][seg * 16 + j]);
    pmax[r][seg] = pm;
    __syncthreads();
    if (tid < 64) {
      float tm = fmaxf(fmaxf(pmax[tid][0], pmax[tid][1]),
                       fmaxf(pmax[tid][2], pmax[tid][3]));
      float M = fmaxf(mS[tid], tm);
      corrS[tid] = __expf(mS[tid] - M);
      mS[tid] = M;
    }
    __syncthreads();
    float M = mS[r];
    float psu = 0.f;
    for (int j = 0; j < 16; j++) {
      float e = __expf(Ps[r][seg * 16 + j] - M);
      Ps[r][seg * 16 + j] = e;
      psu += e;
    }
    psum[r][seg] = psu;
    // rescale accumulators by corr of each owned query row
    float cr[4];
#pragma unroll
    for (int i = 0; i < 4; i++) cr[i] = corrS[ty * 4 + i];
#pragma unroll
    for (int i = 0; i < 4; i++)
#pragma unroll
      for (int j = 0; j < 4; j++) acc[i][j] *= cr[i];
    __syncthreads();
    if (tid < 64)
      lS[tid] = lS[tid] * corrS[tid] +
                psum[tid][0] + psum[tid][1] + psum[tid][2] + psum[tid][3];

    // PV: acc[qi][ci] += sum_s P[q][s] * V[s][c]
    for (int s = 0; s < 64; s++) {
      float4 vv = *(const float4*)&VsT[s][tx * 4];  // 2-way, free
      float va[4] = {vv.x, vv.y, vv.z, vv.w};
      float pq[4];
#pragma unroll
      for (int i = 0; i < 4; i++) pq[i] = Ps[ty * 4 + i][s];  // broadcast
#pragma unroll
      for (int i = 0; i < 4; i++)
#pragma unroll
        for (int j = 0; j < 4; j++)
          acc[i][j] = fmaf(pq[i], va[j], acc[i][j]);
    }
    __syncthreads();   // protects lS + next tile's LDS overwrite
  }

  // normalize and store via LDS transpose (reuse Ps as [ch][q])
  float inv[4];
#pragma unroll
  for (int i = 0; i < 4; i++) inv[i] = 1.f / lS[ty * 4 + i];
#pragma unroll
  for (int j = 0; j < 4; j++)
    *(float4*)&Ps[tx * 4 + j][ty * 4] =
        make_float4(acc[0][j] * inv[0], acc[1][j] * inv[1],
                    acc[2][j] * inv[2], acc[3][j] * inv[3]);
  __syncthreads();
  float* ap = aout + ((size_t)b * CC + (size_t)hh * 64) * TT;
  for (int i = tid; i < 1024; i += 256) {
    int c = i >> 4, q4 = (i & 15) * 4;
    *(float4*)&ap[(size_t)c * TT + qt0 + q4] = *(const float4*)&Ps[c][q4];
  }
}

// ---------------------------------------------------------------------------
extern "C" void kernel_launch(void* const* d_in, const int* in_sizes, int n_in,
                              void* d_out, int out_size, void* d_ws, size_t ws_size,
                              hipStream_t stream) {
  (void)in_sizes; (void)n_in; (void)out_size; (void)ws_size;
  const float* x      = (const float*)d_in[0];
  const float* norm_w = (const float*)d_in[1];
  const float* norm_b = (const float*)d_in[2];
  const float* qkv_w  = (const float*)d_in[3];
  const float* qkv_b  = (const float*)d_in[4];
  const float* proj_w = (const float*)d_in[5];
  const float* proj_b = (const float*)d_in[6];
  float* out = (float*)d_out;
  float* ws  = (float*)d_ws;

  // ws layout (floats):  [0, 4194304)        h   (dead after QKV GEMM, reused as a)
  //                      [4194304, 16777216) qkv
  float* h   = ws;
  float* qkv = ws + (size_t)BB * CC * TT;       // 4,194,304
  float* a   = ws;                               // reuse h region
  // total ws requirement: 16,777,216 floats = 64 MiB

  gn_kernel<<<BB * GG, 256, 0, stream>>>(x, norm_w, norm_b, h);
  gemm_kernel<false><<<dim3(TT / 128, 1536 / 128, BB), 256, 0, stream>>>(
      qkv_w, h, qkv_b, nullptr, qkv, 1536);
  attn_kernel<<<dim3(TT / 64, BB * HEADS), 256, 0, stream>>>(qkv, a);
  gemm_kernel<true><<<dim3(TT / 128, CC / 128, BB), 256, 0, stream>>>(
      proj_w, a, proj_b, x, out, CC);
}

// Round 6
// 474.948 us; speedup vs baseline: 2.2917x; 2.2917x over previous
//
#include <hip/hip_runtime.h>
#include <math.h>

// Problem constants (B,C,T fixed by setup_inputs)
#define BB 4
#define CC 512
#define TT 2048
#define GG 32
#define HEADS 8
#define CPG (CC/GG)        // 16 channels per group
#define GN_N (CPG*TT)      // 32768 elements per group
#define EPS 1e-5f

// ---------------------------------------------------------------------------
// Kernel 1: GroupNorm (unchanged from validated baseline).
// ---------------------------------------------------------------------------
__global__ __launch_bounds__(256) void gn_kernel(
    const float* __restrict__ x, const float* __restrict__ w,
    const float* __restrict__ bvec, float* __restrict__ h) {
  int bg = blockIdx.x;            // b*GG + g
  int b = bg / GG, g = bg % GG;
  const float* xp = x + ((size_t)b * CC + (size_t)g * CPG) * TT;
  float* hp = h + ((size_t)b * CC + (size_t)g * CPG) * TT;
  int tid = threadIdx.x;

  float s = 0.f, ss = 0.f;
  const float4* x4 = (const float4*)xp;
  for (int i = tid; i < GN_N / 4; i += 256) {
    float4 v = x4[i];
    s  += v.x + v.y + v.z + v.w;
    ss += v.x * v.x + v.y * v.y + v.z * v.z + v.w * v.w;
  }
  for (int off = 32; off > 0; off >>= 1) {
    s  += __shfl_down(s, off);
    ss += __shfl_down(ss, off);
  }
  __shared__ float red[2][4];
  __shared__ float mu_s, rstd_s;
  int wid = tid >> 6;
  if ((tid & 63) == 0) { red[0][wid] = s; red[1][wid] = ss; }
  __syncthreads();
  if (tid == 0) {
    float S = 0.f, SS = 0.f;
    for (int i = 0; i < 4; i++) { S += red[0][i]; SS += red[1][i]; }
    float mu  = S / (float)GN_N;
    float var = SS / (float)GN_N - mu * mu;
    mu_s = mu; rstd_s = rsqrtf(var + EPS);
  }
  __syncthreads();
  float mu = mu_s, rstd = rstd_s;
  float4* h4 = (float4*)hp;
  for (int i = tid; i < GN_N / 4; i += 256) {
    int c = g * CPG + (i * 4) / TT;
    float sw = w[c] * rstd;
    float sb = bvec[c] - mu * sw;
    float4 v = x4[i];
    float4 o;
    o.x = v.x * sw + sb; o.y = v.y * sw + sb;
    o.z = v.z * sw + sb; o.w = v.w * sw + sb;
    h4[i] = o;
  }
}

// ---------------------------------------------------------------------------
// Kernel 2/4: fp32 SGEMM (unchanged from validated baseline).
// ---------------------------------------------------------------------------
template <bool ADD_RES>
__global__ __launch_bounds__(256) void gemm_kernel(
    const float* __restrict__ A,     // M x 512, row-major
    const float* __restrict__ Bm,    // B x 512 x T
    const float* __restrict__ bias,  // M
    const float* __restrict__ resid, // B x M x T (only when ADD_RES)
    float* __restrict__ Cm,          // B x M x T
    int M) {
  const int K = 512;
  int b  = blockIdx.z;
  int n0 = blockIdx.x * 128;
  int m0 = blockIdx.y * 128;
  const float* Bp = Bm + (size_t)b * K * TT;
  float* Cp = Cm + (size_t)b * M * TT;

  __shared__ float As[16][132];
  __shared__ float Bs[16][128];

  int tid = threadIdx.x;
  int tx = tid & 15, ty = tid >> 4;

  float acc[8][8];
#pragma unroll
  for (int i = 0; i < 8; i++)
#pragma unroll
    for (int j = 0; j < 8; j++) acc[i][j] = 0.f;

  int la_m = tid >> 2;
  int la_k = (tid & 3) * 4;
  int lb_k = tid >> 5;
  int lb_n = (tid & 31) * 4;

  for (int k0 = 0; k0 < K; k0 += 16) {
    float4 a0 = *(const float4*)&A[(size_t)(m0 + la_m) * K + k0 + la_k];
    float4 a1 = *(const float4*)&A[(size_t)(m0 + 64 + la_m) * K + k0 + la_k];
    float4 b0 = *(const float4*)&Bp[(size_t)(k0 + lb_k) * TT + n0 + lb_n];
    float4 b1 = *(const float4*)&Bp[(size_t)(k0 + 8 + lb_k) * TT + n0 + lb_n];
    __syncthreads();
    As[la_k + 0][la_m] = a0.x; As[la_k + 1][la_m] = a0.y;
    As[la_k + 2][la_m] = a0.z; As[la_k + 3][la_m] = a0.w;
    As[la_k + 0][64 + la_m] = a1.x; As[la_k + 1][64 + la_m] = a1.y;
    As[la_k + 2][64 + la_m] = a1.z; As[la_k + 3][64 + la_m] = a1.w;
    *(float4*)&Bs[lb_k][lb_n] = b0;
    *(float4*)&Bs[lb_k + 8][lb_n] = b1;
    __syncthreads();
#pragma unroll
    for (int k = 0; k < 16; k++) {
      float4 av0 = *(const float4*)&As[k][ty * 4];
      float4 av1 = *(const float4*)&As[k][64 + ty * 4];
      float4 bv0 = *(const float4*)&Bs[k][tx * 4];
      float4 bv1 = *(const float4*)&Bs[k][64 + tx * 4];
      float am[8] = {av0.x, av0.y, av0.z, av0.w, av1.x, av1.y, av1.z, av1.w};
      float bn[8] = {bv0.x, bv0.y, bv0.z, bv0.w, bv1.x, bv1.y, bv1.z, bv1.w};
#pragma unroll
      for (int i = 0; i < 8; i++)
#pragma unroll
        for (int j = 0; j < 8; j++)
          acc[i][j] = fmaf(am[i], bn[j], acc[i][j]);
    }
  }
#pragma unroll
  for (int ih = 0; ih < 2; ih++) {
#pragma unroll
    for (int i = 0; i < 4; i++) {
      int m = m0 + ih * 64 + ty * 4 + i;
      float bb = bias[m];
#pragma unroll
      for (int jh = 0; jh < 2; jh++) {
        int n = n0 + jh * 64 + tx * 4;
        float4 r;
        r.x = acc[ih * 4 + i][jh * 4 + 0] + bb;
        r.y = acc[ih * 4 + i][jh * 4 + 1] + bb;
        r.z = acc[ih * 4 + i][jh * 4 + 2] + bb;
        r.w = acc[ih * 4 + i][jh * 4 + 3] + bb;
        if (ADD_RES) {
          float4 xv = *(const float4*)&resid[(size_t)b * M * TT + (size_t)m * TT + n];
          r.x += xv.x; r.y += xv.y; r.z += xv.z; r.w += xv.w;
        }
        *(float4*)&Cp[(size_t)m * TT + n] = r;
      }
    }
  }
}

// ---------------------------------------------------------------------------
// Kernel 3: MFMA flash attention (bf16x3 QK^T, bf16 PV, fp32 softmax in regs).
//
// Block = (bh, 64-query tile), 256 thr = 4 waves; wave w owns q-rows w*16..+15.
// Orientation: S^T = K^T · Q  per 16x16x32 MFMA:
//   A = K^T  (rows s, k=c)  from Kh/Kl[s][c]   (staged transposed + hi/lo split)
//   B = Q    (k=c, cols q)  from Qh/Ql[q][c]   (staged once, transposed + split)
//   D[s][q]: lane holds col q = l&15, rows s = sf*16 + 4*(l>>4) + r.
// => softmax over s is per-lane (16 regs) + shfl_xor(16) + shfl_xor(32). No LDS.
// P stored bf16 to Pb[q][s] (per-wave rows only, no cross-wave barrier needed),
// PV: A = P[q][s], B = V[s][c] from Vn[c][s] (natural layout), D = O[q][c].
// All bf16 LDS tiles: [64][64] shorts, XOR swizzle idx ^= ((row>>2)&3)<<4
// applied to every write AND read (keeps 16B frag reads conflict-optimal).
// ---------------------------------------------------------------------------
typedef __attribute__((ext_vector_type(8))) short s16x8;
typedef __attribute__((ext_vector_type(4))) float f32x4;

__device__ __forceinline__ unsigned short bfh(float x) {
  unsigned int u = __float_as_uint(x);
  return (unsigned short)((u + 0x7FFFu + ((u >> 16) & 1u)) >> 16);  // RNE
}
__device__ __forceinline__ float bf2f(unsigned short h) {
  return __uint_as_float(((unsigned int)h) << 16);
}
__device__ __forceinline__ int swz(int r, int c) {
  return (r << 6) + (c ^ (((r >> 2) & 3) << 4));
}

__global__ __launch_bounds__(256, 3) void attn_kernel(
    const float* __restrict__ qkv,  // B x 1536 x T
    float* __restrict__ aout) {     // B x 512 x T
  __shared__ unsigned short Qh[4096], Ql[4096];   // [q][c] hi/lo
  __shared__ unsigned short Kh[4096], Kl[4096];   // [s][c] hi/lo
  __shared__ unsigned short Vn[4096];             // [c][s]
  __shared__ unsigned short Pb[4096];             // [q][s]

  int bh = blockIdx.y;
  int b = bh / HEADS, hh = bh % HEADS;
  int qt0 = blockIdx.x * 64;
  const float* qp = qkv + ((size_t)b * 1536 + (size_t)hh * 192) * TT;
  const float* kp = qp + (size_t)64 * TT;
  const float* vp = qp + (size_t)128 * TT;

  int tid = threadIdx.x;
  int l = tid & 63, w = tid >> 6;
  int g = l >> 4, li = l & 15;
  int wq0 = w * 16;
  const float scale2 = 0.125f;  // 1/sqrt(64), folded into Q only

  // ---- stage Q (transposed + hi/lo split), once per block ----
#pragma unroll
  for (int it = 0; it < 2; it++) {
    int ii = tid + it * 256;           // 0..511
    int q4 = (ii & 15) * 4;
    int c2 = (ii >> 4) * 2;
    float4 fa = *(const float4*)&qp[(size_t)c2 * TT + qt0 + q4];
    float4 fb = *(const float4*)&qp[(size_t)(c2 + 1) * TT + qt0 + q4];
    float va[4] = {fa.x, fa.y, fa.z, fa.w};
    float vb[4] = {fb.x, fb.y, fb.z, fb.w};
#pragma unroll
    for (int j = 0; j < 4; j++) {
      float xa = va[j] * scale2, xb = vb[j] * scale2;
      unsigned short ha = bfh(xa), hb = bfh(xb);
      unsigned short la = bfh(xa - bf2f(ha)), lb = bfh(xb - bf2f(hb));
      int idx = swz(q4 + j, c2);
      *(ushort2*)&Qh[idx] = make_ushort2(ha, hb);
      *(ushort2*)&Ql[idx] = make_ushort2(la, lb);
    }
  }
  __syncthreads();

  // B=Q fragments, held in registers for the whole kernel
  s16x8 qfh[2], qfl[2];
  {
    int row = wq0 + li;
    qfh[0] = *(const s16x8*)&Qh[swz(row, g * 8)];
    qfh[1] = *(const s16x8*)&Qh[swz(row, 32 + g * 8)];
    qfl[0] = *(const s16x8*)&Ql[swz(row, g * 8)];
    qfl[1] = *(const s16x8*)&Ql[swz(row, 32 + g * 8)];
  }

  float m_run = -INFINITY, l_run = 0.f;
  f32x4 oacc[4];
#pragma unroll
  for (int i = 0; i < 4; i++) oacc[i] = (f32x4){0.f, 0.f, 0.f, 0.f};

  for (int s0 = 0; s0 < TT; s0 += 64) {
    __syncthreads();   // all waves done reading prev tile's K/V
    // ---- stage K (transposed + split) ----
#pragma unroll
    for (int it = 0; it < 2; it++) {
      int ii = tid + it * 256;
      int s4 = (ii & 15) * 4;
      int c2 = (ii >> 4) * 2;
      float4 fa = *(const float4*)&kp[(size_t)c2 * TT + s0 + s4];
      float4 fb = *(const float4*)&kp[(size_t)(c2 + 1) * TT + s0 + s4];
      float va[4] = {fa.x, fa.y, fa.z, fa.w};
      float vb[4] = {fb.x, fb.y, fb.z, fb.w};
#pragma unroll
      for (int j = 0; j < 4; j++) {
        unsigned short ha = bfh(va[j]), hb = bfh(vb[j]);
        unsigned short la = bfh(va[j] - bf2f(ha)), lb = bfh(vb[j] - bf2f(hb));
        int idx = swz(s4 + j, c2);
        *(ushort2*)&Kh[idx] = make_ushort2(ha, hb);
        *(ushort2*)&Kl[idx] = make_ushort2(la, lb);
      }
    }
    // ---- stage V (natural [c][s], bf16) ----
#pragma unroll
    for (int it = 0; it < 4; it++) {
      int ii = tid + it * 256;
      int c = ii >> 4, s4 = (ii & 15) * 4;
      float4 fv = *(const float4*)&vp[(size_t)c * TT + s0 + s4];
      *(ushort4*)&Vn[swz(c, s4)] =
          make_ushort4(bfh(fv.x), bfh(fv.y), bfh(fv.z), bfh(fv.w));
    }
    __syncthreads();

    // ---- QK^T: sacc[sf] = S^T rows sf*16..+15, cols wq0..wq0+15 ----
    f32x4 sacc[4];
#pragma unroll
    for (int sf = 0; sf < 4; sf++) sacc[sf] = (f32x4){0.f, 0.f, 0.f, 0.f};
#pragma unroll
    for (int sf = 0; sf < 4; sf++) {
      int row = sf * 16 + li;
#pragma unroll
      for (int ch = 0; ch < 2; ch++) {
        s16x8 kfh = *(const s16x8*)&Kh[swz(row, ch * 32 + g * 8)];
        s16x8 kfl = *(const s16x8*)&Kl[swz(row, ch * 32 + g * 8)];
        sacc[sf] = __builtin_amdgcn_mfma_f32_16x16x32_bf16(kfh, qfh[ch], sacc[sf], 0, 0, 0);
        sacc[sf] = __builtin_amdgcn_mfma_f32_16x16x32_bf16(kfh, qfl[ch], sacc[sf], 0, 0, 0);
        sacc[sf] = __builtin_amdgcn_mfma_f32_16x16x32_bf16(kfl, qfh[ch], sacc[sf], 0, 0, 0);
      }
    }

    // ---- online softmax, fully in registers (lane's q = wq0+li) ----
    float tmax = sacc[0][0];
#pragma unroll
    for (int sf = 0; sf < 4; sf++)
#pragma unroll
      for (int r = 0; r < 4; r++) tmax = fmaxf(tmax, sacc[sf][r]);
    tmax = fmaxf(tmax, __shfl_xor(tmax, 16));
    tmax = fmaxf(tmax, __shfl_xor(tmax, 32));
    float Mn = fmaxf(m_run, tmax);
    float corr = __expf(m_run - Mn);
    m_run = Mn;
    float psum = 0.f;
#pragma unroll
    for (int sf = 0; sf < 4; sf++) {
      float p0 = __expf(sacc[sf][0] - Mn), p1 = __expf(sacc[sf][1] - Mn);
      float p2 = __expf(sacc[sf][2] - Mn), p3 = __expf(sacc[sf][3] - Mn);
      psum += (p0 + p1) + (p2 + p3);
      *(ushort4*)&Pb[swz(wq0 + li, sf * 16 + g * 4)] =
          make_ushort4(bfh(p0), bfh(p1), bfh(p2), bfh(p3));
    }
    psum += __shfl_xor(psum, 16);
    psum += __shfl_xor(psum, 32);
    l_run = l_run * corr + psum;

    // rescale factors for O rows q_local = 4g + r (stats live at lane li = q_local)
    float c0 = __shfl(corr, 4 * g + 0), c1 = __shfl(corr, 4 * g + 1);
    float c2v = __shfl(corr, 4 * g + 2), c3 = __shfl(corr, 4 * g + 3);

    // ---- PV: O[q][c] += P · V ----
    s16x8 pa0 = *(const s16x8*)&Pb[swz(wq0 + li, g * 8)];
    s16x8 pa1 = *(const s16x8*)&Pb[swz(wq0 + li, 32 + g * 8)];
#pragma unroll
    for (int cf = 0; cf < 4; cf++) {
      f32x4 o = oacc[cf];
      o[0] *= c0; o[1] *= c1; o[2] *= c2v; o[3] *= c3;
      s16x8 vb0 = *(const s16x8*)&Vn[swz(cf * 16 + li, g * 8)];
      s16x8 vb1 = *(const s16x8*)&Vn[swz(cf * 16 + li, 32 + g * 8)];
      o = __builtin_amdgcn_mfma_f32_16x16x32_bf16(pa0, vb0, o, 0, 0, 0);
      o = __builtin_amdgcn_mfma_f32_16x16x32_bf16(pa1, vb1, o, 0, 0, 0);
      oacc[cf] = o;
    }
  }

  // ---- epilogue: normalize and store (lane: col c = cf*16+li, rows 4g..4g+3) ----
  float i0 = 1.f / __shfl(l_run, 4 * g + 0), i1 = 1.f / __shfl(l_run, 4 * g + 1);
  float i2 = 1.f / __shfl(l_run, 4 * g + 2), i3 = 1.f / __shfl(l_run, 4 * g + 3);
  float* ap = aout + ((size_t)b * CC + (size_t)hh * 64) * TT;
#pragma unroll
  for (int cf = 0; cf < 4; cf++) {
    int c = cf * 16 + li;
    float4 o4 = make_float4(oacc[cf][0] * i0, oacc[cf][1] * i1,
                            oacc[cf][2] * i2, oacc[cf][3] * i3);
    *(float4*)&ap[(size_t)c * TT + qt0 + wq0 + g * 4] = o4;
  }
}

// ---------------------------------------------------------------------------
extern "C" void kernel_launch(void* const* d_in, const int* in_sizes, int n_in,
                              void* d_out, int out_size, void* d_ws, size_t ws_size,
                              hipStream_t stream) {
  (void)in_sizes; (void)n_in; (void)out_size; (void)ws_size;
  const float* x      = (const float*)d_in[0];
  const float* norm_w = (const float*)d_in[1];
  const float* norm_b = (const float*)d_in[2];
  const float* qkv_w  = (const float*)d_in[3];
  const float* qkv_b  = (const float*)d_in[4];
  const float* proj_w = (const float*)d_in[5];
  const float* proj_b = (const float*)d_in[6];
  float* out = (float*)d_out;
  float* ws  = (float*)d_ws;

  float* h   = ws;
  float* qkv = ws + (size_t)BB * CC * TT;       // 4,194,304 floats in
  float* a   = ws;                               // reuse h region
  // total ws requirement: 16,777,216 floats = 64 MiB

  gn_kernel<<<BB * GG, 256, 0, stream>>>(x, norm_w, norm_b, h);
  gemm_kernel<false><<<dim3(TT / 128, 1536 / 128, BB), 256, 0, stream>>>(
      qkv_w, h, qkv_b, nullptr, qkv, 1536);
  attn_kernel<<<dim3(TT / 64, BB * HEADS), 256, 0, stream>>>(qkv, a);
  gemm_kernel<true><<<dim3(TT / 128, CC / 128, BB), 256, 0, stream>>>(
      proj_w, a, proj_b, x, out, CC);
}

// Round 7
// 319.888 us; speedup vs baseline: 3.4026x; 1.4847x over previous
//
#include <hip/hip_runtime.h>
#include <math.h>

#define BB 4
#define CC 512
#define TT 2048
#define GG 32
#define HEADS 8
#define CPG 16
#define GN_N (CPG*TT)
#define EPS 1e-5f

typedef __attribute__((ext_vector_type(8))) short s16x8;
typedef __attribute__((ext_vector_type(4))) float f32x4;
typedef unsigned short u16;
typedef unsigned int u32;

__device__ __forceinline__ u16 bfh(float x) {
  u32 u = __float_as_uint(x);
  return (u16)((u + 0x7FFFu + ((u >> 16) & 1u)) >> 16);  // RNE bf16
}
__device__ __forceinline__ float bf2f(u16 h) {
  return __uint_as_float(((u32)h) << 16);
}
__device__ __forceinline__ int swz(int r, int c) {       // attn 64x64 tile swizzle
  return (r << 6) + (c ^ (((r >> 2) & 3) << 4));
}

// ---------------------------------------------------------------------------
// Kernel 1a: GroupNorm stats. Block = (b,g): reduce 16ch x 2048 contiguous.
// ---------------------------------------------------------------------------
__global__ __launch_bounds__(256) void gn_stats(const float* __restrict__ x,
                                                float2* __restrict__ stats) {
  int bg = blockIdx.x;
  const float* xp = x + (size_t)bg * (CPG * TT);
  int tid = threadIdx.x;
  float s = 0.f, ss = 0.f;
  const float4* x4 = (const float4*)xp;
  for (int i = tid; i < GN_N / 4; i += 256) {
    float4 v = x4[i];
    s += v.x + v.y + v.z + v.w;
    ss += v.x * v.x + v.y * v.y + v.z * v.z + v.w * v.w;
  }
  for (int off = 32; off > 0; off >>= 1) {
    s += __shfl_down(s, off);
    ss += __shfl_down(ss, off);
  }
  __shared__ float red[2][4];
  int wid = tid >> 6;
  if ((tid & 63) == 0) { red[0][wid] = s; red[1][wid] = ss; }
  __syncthreads();
  if (tid == 0) {
    float S = 0.f, SS = 0.f;
    for (int i = 0; i < 4; i++) { S += red[0][i]; SS += red[1][i]; }
    float mu = S / (float)GN_N;
    float var = SS / (float)GN_N - mu * mu;
    stats[bg] = make_float2(mu, rsqrtf(var + EPS));
  }
}

// ---------------------------------------------------------------------------
// Kernel 1b: GroupNorm normalize + bf16 hi/lo split + TRANSPOSE to [b][t][c].
// Block = (b, 32-t slab); two 16-t sub-passes through a padded LDS tile
// (pad 514 uints: write banks 2-way, b128 readback ~min). Output rows are
// [t][512c] bf16 planes -> GEMM A-operand staging becomes pure b128 copies.
// ---------------------------------------------------------------------------
__global__ __launch_bounds__(256) void gn_norm_t(
    const float* __restrict__ x, const float* __restrict__ w,
    const float* __restrict__ bv, const float2* __restrict__ stats,
    u16* __restrict__ hthi, u16* __restrict__ htlo) {
  __shared__ u32 Lt[16 * 514];   // [t16][c512+pad] packed (hi | lo<<16)
  int b = blockIdx.y;
  int t0 = blockIdx.x * 32;
  int tid = threadIdx.x;
  const float* xb = x + (size_t)b * CC * TT;

  for (int half = 0; half < 2; half++) {
    int tbase = t0 + half * 16;
    if (half) __syncthreads();          // previous readout done
#pragma unroll
    for (int it = 0; it < 8; it++) {
      int mt = tid + it * 256;          // 0..2047
      int c = mt >> 2;                  // 0..511
      int t4 = (mt & 3) * 4;            // 0,4,8,12
      float4 v = *(const float4*)&xb[(size_t)c * TT + tbase + t4];
      float2 st = stats[b * GG + (c >> 4)];
      float sw = w[c] * st.y;
      float sb = bv[c] - st.x * sw;
      float vals[4] = {v.x * sw + sb, v.y * sw + sb, v.z * sw + sb, v.w * sw + sb};
#pragma unroll
      for (int j = 0; j < 4; j++) {
        u16 h = bfh(vals[j]);
        u16 lo = bfh(vals[j] - bf2f(h));
        Lt[(t4 + j) * 514 + c] = (u32)h | ((u32)lo << 16);
      }
    }
    __syncthreads();
    // readout: t = tid>>4 (16 rows), 16 threads/row, 32 c each
    int t = tid >> 4;
    u16* dh = hthi + ((size_t)b * TT + tbase + t) * CC;
    u16* dl = htlo + ((size_t)b * TT + tbase + t) * CC;
#pragma unroll
    for (int j = 0; j < 2; j++) {
      int c0 = (tid & 15) * 16 + j * 256;
      const u32* Lr = &Lt[t * 514 + c0];
      uint4 a = *(const uint4*)&Lr[0];
      uint4 bq = *(const uint4*)&Lr[4];
      uint4 cq = *(const uint4*)&Lr[8];
      uint4 dq = *(const uint4*)&Lr[12];
      uint4 h1 = make_uint4((a.x & 0xFFFFu) | (a.y << 16), (a.z & 0xFFFFu) | (a.w << 16),
                            (bq.x & 0xFFFFu) | (bq.y << 16), (bq.z & 0xFFFFu) | (bq.w << 16));
      uint4 h2 = make_uint4((cq.x & 0xFFFFu) | (cq.y << 16), (cq.z & 0xFFFFu) | (cq.w << 16),
                            (dq.x & 0xFFFFu) | (dq.y << 16), (dq.z & 0xFFFFu) | (dq.w << 16));
      uint4 l1 = make_uint4((a.x >> 16) | (a.y & 0xFFFF0000u), (a.z >> 16) | (a.w & 0xFFFF0000u),
                            (bq.x >> 16) | (bq.y & 0xFFFF0000u), (bq.z >> 16) | (bq.w & 0xFFFF0000u));
      uint4 l2 = make_uint4((cq.x >> 16) | (cq.y & 0xFFFF0000u), (cq.z >> 16) | (cq.w & 0xFFFF0000u),
                            (dq.x >> 16) | (dq.y & 0xFFFF0000u), (dq.z >> 16) | (dq.w & 0xFFFF0000u));
      *(uint4*)&dh[c0] = h1; *(uint4*)&dh[c0 + 8] = h2;
      *(uint4*)&dl[c0] = l1; *(uint4*)&dl[c0 + 8] = l2;
    }
  }
}

// ---------------------------------------------------------------------------
// Kernel 2: weight convert: [qkv_w ; proj_w] fp32 -> bf16 hi/lo planes [m][k].
// ---------------------------------------------------------------------------
__global__ __launch_bounds__(256) void wconv(const float* __restrict__ qw,
                                             const float* __restrict__ pw,
                                             u16* __restrict__ whi, u16* __restrict__ wlo) {
  const int NQ = 1536 * 512;
  int idx4 = (blockIdx.x * 256 + threadIdx.x) * 4;
  float4 v = (idx4 < NQ) ? *(const float4*)&qw[idx4]
                         : *(const float4*)&pw[idx4 - NQ];
  u16 hx = bfh(v.x), hy = bfh(v.y), hz = bfh(v.z), hw = bfh(v.w);
  *(ushort4*)&whi[idx4] = make_ushort4(hx, hy, hz, hw);
  *(ushort4*)&wlo[idx4] = make_ushort4(bfh(v.x - bf2f(hx)), bfh(v.y - bf2f(hy)),
                                       bfh(v.z - bf2f(hz)), bfh(v.w - bf2f(hw)));
}

// ---------------------------------------------------------------------------
// Kernel 3/5: bf16x3 MFMA GEMM.  D[t][m] = sum_k Xt[t][k] * W[m][k]  (+bias).
// A-operand = Xt (h_t or a_t, bf16 hi/lo planes [b][2048][512]);
// B-operand = W planes [m][512].  Tile 128t x 128m, BK=32, 4 waves (2x2).
// LDS granule swizzle u = row*4 + (k8 ^ ((row>>2)&3)) -> uniform 8/bank b128.
// D-frag rows are t (4 consecutive per lane) -> float4 stores along t.
// QKV epilogue: q/k rows -> fp32 qk buffer; v rows -> bf16 vbuf (round-6-equal
// numerics: attn converted v to bf16 anyway).  Proj: +proj_b +x -> d_out.
// ---------------------------------------------------------------------------
template <bool QKV>
__global__ __launch_bounds__(256) void gemm_t(
    const u16* __restrict__ Ahi, const u16* __restrict__ Alo,
    const u16* __restrict__ Whi_, const u16* __restrict__ Wlo_,
    const float* __restrict__ bias, const float* __restrict__ resid,
    float* __restrict__ outf, u16* __restrict__ outv) {
  __shared__ u16 At[2][4096];
  __shared__ u16 Bt[2][4096];
  int tid = threadIdx.x;
  int l = tid & 63, w = tid >> 6;
  int g = l >> 4, li = l & 15;
  int t0 = blockIdx.x * 128, m0 = blockIdx.y * 128, b = blockIdx.z;
  int wt = w & 1, wm = w >> 1;
  const u16* Abh = Ahi + ((size_t)b * TT + t0) * 512;
  const u16* Abl = Alo + ((size_t)b * TT + t0) * 512;
  const u16* Wbh = Whi_ + (size_t)m0 * 512;
  const u16* Wbl = Wlo_ + (size_t)m0 * 512;

  f32x4 dacc[4][4];
#pragma unroll
  for (int i = 0; i < 4; i++)
#pragma unroll
    for (int j = 0; j < 4; j++) dacc[i][j] = (f32x4){0.f, 0.f, 0.f, 0.f};

  for (int k0 = 0; k0 < 512; k0 += 32) {
    s16x8 rah[2], ral[2], rbh[2], rbl[2];
#pragma unroll
    for (int it = 0; it < 2; it++) {           // issue loads before barrier
      int gi = l + 64 * it;
      int rr = w * 32 + (gi >> 2);             // staging row (t for A, m for B)
      int k8 = gi & 3;
      size_t ga = (size_t)rr * 512 + k0 + k8 * 8;
      rah[it] = *(const s16x8*)&Abh[ga];
      ral[it] = *(const s16x8*)&Abl[ga];
      rbh[it] = *(const s16x8*)&Wbh[ga];
      rbl[it] = *(const s16x8*)&Wbl[ga];
    }
    __syncthreads();                            // prev iter frag reads done
#pragma unroll
    for (int it = 0; it < 2; it++) {
      int gi = l + 64 * it;
      int rr = w * 32 + (gi >> 2);
      int k8 = gi & 3;
      int u = rr * 4 + (k8 ^ ((rr >> 2) & 3));
      *(s16x8*)&At[0][u * 8] = rah[it];
      *(s16x8*)&At[1][u * 8] = ral[it];
      *(s16x8*)&Bt[0][u * 8] = rbh[it];
      *(s16x8*)&Bt[1][u * 8] = rbl[it];
    }
    __syncthreads();
    s16x8 bh[4], bl[4];
#pragma unroll
    for (int mb = 0; mb < 4; mb++) {
      int m = wm * 64 + mb * 16 + li;
      int u = m * 4 + (g ^ ((m >> 2) & 3));
      bh[mb] = *(const s16x8*)&Bt[0][u * 8];
      bl[mb] = *(const s16x8*)&Bt[1][u * 8];
    }
#pragma unroll
    for (int tb = 0; tb < 4; tb++) {
      int t = wt * 64 + tb * 16 + li;
      int u = t * 4 + (g ^ ((t >> 2) & 3));
      s16x8 ah = *(const s16x8*)&At[0][u * 8];
      s16x8 al = *(const s16x8*)&At[1][u * 8];
#pragma unroll
      for (int mb = 0; mb < 4; mb++) {
        dacc[tb][mb] = __builtin_amdgcn_mfma_f32_16x16x32_bf16(ah, bh[mb], dacc[tb][mb], 0, 0, 0);
        dacc[tb][mb] = __builtin_amdgcn_mfma_f32_16x16x32_bf16(ah, bl[mb], dacc[tb][mb], 0, 0, 0);
        dacc[tb][mb] = __builtin_amdgcn_mfma_f32_16x16x32_bf16(al, bh[mb], dacc[tb][mb], 0, 0, 0);
      }
    }
  }
  // epilogue: fragment rows = 4 consecutive t at col m = ..+li (branch uniform
  // per fragment: 16-row frags never straddle the 64-row q/k/v segments).
#pragma unroll
  for (int tb = 0; tb < 4; tb++) {
    int t = t0 + wt * 64 + tb * 16 + 4 * g;
#pragma unroll
    for (int mb = 0; mb < 4; mb++) {
      int m = m0 + wm * 64 + mb * 16 + li;
      float bb = bias[m];
      f32x4 v = dacc[tb][mb];
      float4 r = make_float4(v[0] + bb, v[1] + bb, v[2] + bb, v[3] + bb);
      if (QKV) {
        int hh = m / 192, rr = m - hh * 192;
        if (rr < 128) {
          *(float4*)&outf[(((size_t)b * HEADS + hh) * 128 + rr) * TT + t] = r;
        } else {
          *(ushort4*)&outv[(((size_t)b * HEADS + hh) * 64 + (rr - 128)) * TT + t] =
              make_ushort4(bfh(r.x), bfh(r.y), bfh(r.z), bfh(r.w));
        }
      } else {
        size_t o = ((size_t)b * CC + m) * TT + t;
        float4 xv = *(const float4*)&resid[o];
        r.x += xv.x; r.y += xv.y; r.z += xv.z; r.w += xv.w;
        *(float4*)&outf[o] = r;
      }
    }
  }
}

// ---------------------------------------------------------------------------
// Kernel 4: MFMA flash attention (round-6 core, validated).  Changes only:
// (a) V input is bf16 vbuf -> staging is a pure swizzled 16B copy;
// (b) epilogue writes a^T bf16 hi/lo planes [b][t][512] via LDS bounce
//     (reuses dead Qh/Ql region, pad-72 rows);
// (c) q/k come from the split fp32 qk buffer (rows hh*128+{0..63 q,64..127 k}).
// ---------------------------------------------------------------------------
__global__ __launch_bounds__(256, 3) void attn_kernel(
    const float* __restrict__ qk,   // [b][h][128][T] fp32 (q rows 0..63, k 64..127)
    const u16* __restrict__ vbuf,   // [b][h][64][T] bf16
    u16* __restrict__ athi, u16* __restrict__ atlo) {  // a^T planes [b][T][512]
  __shared__ u16 QhQl[8192];                   // Qh | Ql ; reused as epilogue Pe
  __shared__ u16 Kh[4096], Kl[4096];
  __shared__ u16 Vn[4096];
  __shared__ u16 Pb[4096];

  u16* Qh = QhQl;
  u16* Ql = QhQl + 4096;

  int bh = blockIdx.y;
  int b = bh / HEADS, hh = bh % HEADS;
  int qt0 = blockIdx.x * 64;
  const float* qp = qk + ((size_t)(b * HEADS + hh) * 128) * TT;
  const float* kp = qp + (size_t)64 * TT;
  const u16* vp = vbuf + ((size_t)(b * HEADS + hh) * 64) * TT;

  int tid = threadIdx.x;
  int l = tid & 63, w = tid >> 6;
  int g = l >> 4, li = l & 15;
  int wq0 = w * 16;
  const float scale2 = 0.125f;  // 1/sqrt(64) folded into Q

  // ---- stage Q (transposed + hi/lo split), once ----
#pragma unroll
  for (int it = 0; it < 2; it++) {
    int ii = tid + it * 256;
    int q4 = (ii & 15) * 4;
    int c2 = (ii >> 4) * 2;
    float4 fa = *(const float4*)&qp[(size_t)c2 * TT + qt0 + q4];
    float4 fb = *(const float4*)&qp[(size_t)(c2 + 1) * TT + qt0 + q4];
    float va[4] = {fa.x, fa.y, fa.z, fa.w};
    float vb[4] = {fb.x, fb.y, fb.z, fb.w};
#pragma unroll
    for (int j = 0; j < 4; j++) {
      float xa = va[j] * scale2, xb = vb[j] * scale2;
      u16 ha = bfh(xa), hbv = bfh(xb);
      u16 la = bfh(xa - bf2f(ha)), lb = bfh(xb - bf2f(hbv));
      int idx = swz(q4 + j, c2);
      *(ushort2*)&Qh[idx] = make_ushort2(ha, hbv);
      *(ushort2*)&Ql[idx] = make_ushort2(la, lb);
    }
  }
  __syncthreads();

  s16x8 qfh[2], qfl[2];
  {
    int row = wq0 + li;
    qfh[0] = *(const s16x8*)&Qh[swz(row, g * 8)];
    qfh[1] = *(const s16x8*)&Qh[swz(row, 32 + g * 8)];
    qfl[0] = *(const s16x8*)&Ql[swz(row, g * 8)];
    qfl[1] = *(const s16x8*)&Ql[swz(row, 32 + g * 8)];
  }

  float m_run = -INFINITY, l_run = 0.f;
  f32x4 oacc[4];
#pragma unroll
  for (int i = 0; i < 4; i++) oacc[i] = (f32x4){0.f, 0.f, 0.f, 0.f};

  for (int s0 = 0; s0 < TT; s0 += 64) {
    __syncthreads();
    // stage K (fp32 -> transposed hi/lo split)
#pragma unroll
    for (int it = 0; it < 2; it++) {
      int ii = tid + it * 256;
      int s4 = (ii & 15) * 4;
      int c2 = (ii >> 4) * 2;
      float4 fa = *(const float4*)&kp[(size_t)c2 * TT + s0 + s4];
      float4 fb = *(const float4*)&kp[(size_t)(c2 + 1) * TT + s0 + s4];
      float va[4] = {fa.x, fa.y, fa.z, fa.w};
      float vb[4] = {fb.x, fb.y, fb.z, fb.w};
#pragma unroll
      for (int j = 0; j < 4; j++) {
        u16 ha = bfh(va[j]), hbv = bfh(vb[j]);
        u16 la = bfh(va[j] - bf2f(ha)), lb = bfh(vb[j] - bf2f(hbv));
        int idx = swz(s4 + j, c2);
        *(ushort2*)&Kh[idx] = make_ushort2(ha, hbv);
        *(ushort2*)&Kl[idx] = make_ushort2(la, lb);
      }
    }
    // stage V (bf16 input -> swizzled 16B copy, natural [c][s])
#pragma unroll
    for (int it = 0; it < 2; it++) {
      int mt = tid + it * 256;          // 0..511
      int c = mt >> 3, s8 = (mt & 7) * 8;
      s16x8 vv = *(const s16x8*)&vp[(size_t)c * TT + s0 + s8];
      *(s16x8*)&Vn[swz(c, s8)] = vv;
    }
    __syncthreads();

    // QK^T (bf16x3): sacc[sf] = S^T rows sf*16..+15, col q = wq0+li
    f32x4 sacc[4];
#pragma unroll
    for (int sf = 0; sf < 4; sf++) sacc[sf] = (f32x4){0.f, 0.f, 0.f, 0.f};
#pragma unroll
    for (int sf = 0; sf < 4; sf++) {
      int row = sf * 16 + li;
#pragma unroll
      for (int ch = 0; ch < 2; ch++) {
        s16x8 kfh = *(const s16x8*)&Kh[swz(row, ch * 32 + g * 8)];
        s16x8 kfl = *(const s16x8*)&Kl[swz(row, ch * 32 + g * 8)];
        sacc[sf] = __builtin_amdgcn_mfma_f32_16x16x32_bf16(kfh, qfh[ch], sacc[sf], 0, 0, 0);
        sacc[sf] = __builtin_amdgcn_mfma_f32_16x16x32_bf16(kfh, qfl[ch], sacc[sf], 0, 0, 0);
        sacc[sf] = __builtin_amdgcn_mfma_f32_16x16x32_bf16(kfl, qfh[ch], sacc[sf], 0, 0, 0);
      }
    }

    // online softmax in registers
    float tmax = sacc[0][0];
#pragma unroll
    for (int sf = 0; sf < 4; sf++)
#pragma unroll
      for (int r = 0; r < 4; r++) tmax = fmaxf(tmax, sacc[sf][r]);
    tmax = fmaxf(tmax, __shfl_xor(tmax, 16));
    tmax = fmaxf(tmax, __shfl_xor(tmax, 32));
    float Mn = fmaxf(m_run, tmax);
    float corr = __expf(m_run - Mn);
    m_run = Mn;
    float psum = 0.f;
#pragma unroll
    for (int sf = 0; sf < 4; sf++) {
      float p0 = __expf(sacc[sf][0] - Mn), p1 = __expf(sacc[sf][1] - Mn);
      float p2 = __expf(sacc[sf][2] - Mn), p3 = __expf(sacc[sf][3] - Mn);
      psum += (p0 + p1) + (p2 + p3);
      *(ushort4*)&Pb[swz(wq0 + li, sf * 16 + g * 4)] =
          make_ushort4(bfh(p0), bfh(p1), bfh(p2), bfh(p3));
    }
    psum += __shfl_xor(psum, 16);
    psum += __shfl_xor(psum, 32);
    l_run = l_run * corr + psum;

    float c0 = __shfl(corr, 4 * g + 0), c1 = __shfl(corr, 4 * g + 1);
    float c2v = __shfl(corr, 4 * g + 2), c3 = __shfl(corr, 4 * g + 3);

    // PV
    s16x8 pa0 = *(const s16x8*)&Pb[swz(wq0 + li, g * 8)];
    s16x8 pa1 = *(const s16x8*)&Pb[swz(wq0 + li, 32 + g * 8)];
#pragma unroll
    for (int cf = 0; cf < 4; cf++) {
      f32x4 o = oacc[cf];
      o[0] *= c0; o[1] *= c1; o[2] *= c2v; o[3] *= c3;
      s16x8 vb0 = *(const s16x8*)&Vn[swz(cf * 16 + li, g * 8)];
      s16x8 vb1 = *(const s16x8*)&Vn[swz(cf * 16 + li, 32 + g * 8)];
      o = __builtin_amdgcn_mfma_f32_16x16x32_bf16(pa0, vb0, o, 0, 0, 0);
      o = __builtin_amdgcn_mfma_f32_16x16x32_bf16(pa1, vb1, o, 0, 0, 0);
      oacc[cf] = o;
    }
  }

  // ---- epilogue: normalize, split bf16 hi/lo, write a^T planes via LDS ----
  float i0 = 1.f / __shfl(l_run, 4 * g + 0), i1 = 1.f / __shfl(l_run, 4 * g + 1);
  float i2 = 1.f / __shfl(l_run, 4 * g + 2), i3 = 1.f / __shfl(l_run, 4 * g + 3);
  float ir[4] = {i0, i1, i2, i3};
  u16 uh[4][4], ul[4][4];
#pragma unroll
  for (int cf = 0; cf < 4; cf++)
#pragma unroll
    for (int r = 0; r < 4; r++) {
      float v = oacc[cf][r] * ir[r];
      uh[cf][r] = bfh(v);
      ul[cf][r] = bfh(v - bf2f(uh[cf][r]));
    }
  u16* Pe = QhQl;                      // 64 x 72 pad (<= 8192), Qh/Ql dead
#pragma unroll
  for (int plane = 0; plane < 2; plane++) {
    __syncthreads();
#pragma unroll
    for (int cf = 0; cf < 4; cf++)
#pragma unroll
      for (int r = 0; r < 4; r++)
        Pe[(wq0 + 4 * g + r) * 72 + cf * 16 + li] = plane ? ul[cf][r] : uh[cf][r];
    __syncthreads();
    int q = tid >> 2, c0r = (tid & 3) * 16;
    s16x8 v0 = *(const s16x8*)&Pe[q * 72 + c0r];
    s16x8 v1 = *(const s16x8*)&Pe[q * 72 + c0r + 8];
    u16* dst = (plane ? atlo : athi) + ((size_t)b * TT + qt0 + q) * CC + hh * 64;
    *(s16x8*)&dst[c0r] = v0;
    *(s16x8*)&dst[c0r + 8] = v1;
  }
}

// ---------------------------------------------------------------------------
extern "C" void kernel_launch(void* const* d_in, const int* in_sizes, int n_in,
                              void* d_out, int out_size, void* d_ws, size_t ws_size,
                              hipStream_t stream) {
  (void)in_sizes; (void)n_in; (void)out_size; (void)ws_size;
  const float* x      = (const float*)d_in[0];
  const float* norm_w = (const float*)d_in[1];
  const float* norm_b = (const float*)d_in[2];
  const float* qkv_w  = (const float*)d_in[3];
  const float* qkv_b  = (const float*)d_in[4];
  const float* proj_w = (const float*)d_in[5];
  const float* proj_b = (const float*)d_in[6];
  float* out = (float*)d_out;
  char* wsb = (char*)d_ws;

  // ws layout (bytes), total 62,915,584 < 64 MiB (known available):
  u16* hthi   = (u16*)(wsb);                    //  8 MB  h^T hi  (later a^T hi)
  u16* htlo   = (u16*)(wsb + 8388608);          //  8 MB  h^T lo  (later a^T lo)
  float* qk   = (float*)(wsb + 16777216);       // 32 MB  q/k fp32 [b][h][128][T]
  u16* vbuf   = (u16*)(wsb + 50331648);         //  8 MB  v bf16  [b][h][64][T]
  u16* whi    = (u16*)(wsb + 58720256);         //  2 MB  W hi (qkv then proj)
  u16* wlo    = (u16*)(wsb + 60817408);         //  2 MB  W lo
  float2* stats = (float2*)(wsb + 62914560);    //  1 KB

  gn_stats<<<BB * GG, 256, 0, stream>>>(x, stats);
  gn_norm_t<<<dim3(64, BB), 256, 0, stream>>>(x, norm_w, norm_b, stats, hthi, htlo);
  wconv<<<1024, 256, 0, stream>>>(qkv_w, proj_w, whi, wlo);
  gemm_t<true><<<dim3(16, 12, BB), 256, 0, stream>>>(
      hthi, htlo, whi, wlo, qkv_b, nullptr, qk, vbuf);
  attn_kernel<<<dim3(TT / 64, BB * HEADS), 256, 0, stream>>>(qk, vbuf, hthi, htlo);
  gemm_t<false><<<dim3(16, 4, BB), 256, 0, stream>>>(
      hthi, htlo, whi + 786432, wlo + 786432, proj_b, x, out, nullptr);
}

// Round 10
// 300.156 us; speedup vs baseline: 3.6263x; 1.0657x over previous
//
#include <hip/hip_runtime.h>
#include <math.h>

#define BB 4
#define CC 512
#define TT 2048
#define GG 32
#define HEADS 8
#define CPG 16
#define GN_N (CPG*TT)
#define EPS 1e-5f

typedef __attribute__((ext_vector_type(8))) short s16x8;
typedef __attribute__((ext_vector_type(4))) float f32x4;
typedef unsigned short u16;
typedef unsigned int u32;

__device__ __forceinline__ u16 bfh(float x) {
  u32 u = __float_as_uint(x);
  return (u16)((u + 0x7FFFu + ((u >> 16) & 1u)) >> 16);  // RNE bf16
}
__device__ __forceinline__ float bf2f(u16 h) {
  return __uint_as_float(((u32)h) << 16);
}
__device__ __forceinline__ int swz(int r, int c) {       // 64-col tile swizzle
  return (r << 6) + (c ^ (((r >> 2) & 3) << 4));
}

// ---------------------------------------------------------------------------
// Kernel 1a: GroupNorm stats (validated round-7 version).
// ---------------------------------------------------------------------------
__global__ __launch_bounds__(256) void gn_stats(const float* __restrict__ x,
                                                float2* __restrict__ stats) {
  int bg = blockIdx.x;
  const float* xp = x + (size_t)bg * (CPG * TT);
  int tid = threadIdx.x;
  float s = 0.f, ss = 0.f;
  const float4* x4 = (const float4*)xp;
  for (int i = tid; i < GN_N / 4; i += 256) {
    float4 v = x4[i];
    s += v.x + v.y + v.z + v.w;
    ss += v.x * v.x + v.y * v.y + v.z * v.z + v.w * v.w;
  }
  for (int off = 32; off > 0; off >>= 1) {
    s += __shfl_down(s, off);
    ss += __shfl_down(ss, off);
  }
  __shared__ float red[2][4];
  int wid = tid >> 6;
  if ((tid & 63) == 0) { red[0][wid] = s; red[1][wid] = ss; }
  __syncthreads();
  if (tid == 0) {
    float S = 0.f, SS = 0.f;
    for (int i = 0; i < 4; i++) { S += red[0][i]; SS += red[1][i]; }
    float mu = S / (float)GN_N;
    float var = SS / (float)GN_N - mu * mu;
    stats[bg] = make_float2(mu, rsqrtf(var + EPS));
  }
}

// ---------------------------------------------------------------------------
// Kernel 1b: GroupNorm normalize + bf16 hi/lo split + transpose (validated).
// ---------------------------------------------------------------------------
__global__ __launch_bounds__(256) void gn_norm_t(
    const float* __restrict__ x, const float* __restrict__ w,
    const float* __restrict__ bv, const float2* __restrict__ stats,
    u16* __restrict__ hthi, u16* __restrict__ htlo) {
  __shared__ u32 Lt[16 * 514];
  int b = blockIdx.y;
  int t0 = blockIdx.x * 32;
  int tid = threadIdx.x;
  const float* xb = x + (size_t)b * CC * TT;

  for (int half = 0; half < 2; half++) {
    int tbase = t0 + half * 16;
    if (half) __syncthreads();
#pragma unroll
    for (int it = 0; it < 8; it++) {
      int mt = tid + it * 256;
      int c = mt >> 2;
      int t4 = (mt & 3) * 4;
      float4 v = *(const float4*)&xb[(size_t)c * TT + tbase + t4];
      float2 st = stats[b * GG + (c >> 4)];
      float sw = w[c] * st.y;
      float sb = bv[c] - st.x * sw;
      float vals[4] = {v.x * sw + sb, v.y * sw + sb, v.z * sw + sb, v.w * sw + sb};
#pragma unroll
      for (int j = 0; j < 4; j++) {
        u16 h = bfh(vals[j]);
        u16 lo = bfh(vals[j] - bf2f(h));
        Lt[(t4 + j) * 514 + c] = (u32)h | ((u32)lo << 16);
      }
    }
    __syncthreads();
    int t = tid >> 4;
    u16* dh = hthi + ((size_t)b * TT + tbase + t) * CC;
    u16* dl = htlo + ((size_t)b * TT + tbase + t) * CC;
#pragma unroll
    for (int j = 0; j < 2; j++) {
      int c0 = (tid & 15) * 16 + j * 256;
      const u32* Lr = &Lt[t * 514 + c0];
      uint4 a = *(const uint4*)&Lr[0];
      uint4 bq = *(const uint4*)&Lr[4];
      uint4 cq = *(const uint4*)&Lr[8];
      uint4 dq = *(const uint4*)&Lr[12];
      uint4 h1 = make_uint4((a.x & 0xFFFFu) | (a.y << 16), (a.z & 0xFFFFu) | (a.w << 16),
                            (bq.x & 0xFFFFu) | (bq.y << 16), (bq.z & 0xFFFFu) | (bq.w << 16));
      uint4 h2 = make_uint4((cq.x & 0xFFFFu) | (cq.y << 16), (cq.z & 0xFFFFu) | (cq.w << 16),
                            (dq.x & 0xFFFFu) | (dq.y << 16), (dq.z & 0xFFFFu) | (dq.w << 16));
      uint4 l1 = make_uint4((a.x >> 16) | (a.y & 0xFFFF0000u), (a.z >> 16) | (a.w & 0xFFFF0000u),
                            (bq.x >> 16) | (bq.y & 0xFFFF0000u), (bq.z >> 16) | (bq.w & 0xFFFF0000u));
      uint4 l2 = make_uint4((cq.x >> 16) | (cq.y & 0xFFFF0000u), (cq.z >> 16) | (cq.w & 0xFFFF0000u),
                            (dq.x >> 16) | (dq.y & 0xFFFF0000u), (dq.z >> 16) | (dq.w & 0xFFFF0000u));
      *(uint4*)&dh[c0] = h1; *(uint4*)&dh[c0 + 8] = h2;
      *(uint4*)&dl[c0] = l1; *(uint4*)&dl[c0 + 8] = l2;
    }
  }
}

// ---------------------------------------------------------------------------
// Kernel 2: weight convert (validated).
// ---------------------------------------------------------------------------
__global__ __launch_bounds__(256) void wconv(const float* __restrict__ qw,
                                             const float* __restrict__ pw,
                                             u16* __restrict__ whi, u16* __restrict__ wlo) {
  const int NQ = 1536 * 512;
  int idx4 = (blockIdx.x * 256 + threadIdx.x) * 4;
  float4 v = (idx4 < NQ) ? *(const float4*)&qw[idx4]
                         : *(const float4*)&pw[idx4 - NQ];
  u16 hx = bfh(v.x), hy = bfh(v.y), hz = bfh(v.z), hw = bfh(v.w);
  *(ushort4*)&whi[idx4] = make_ushort4(hx, hy, hz, hw);
  *(ushort4*)&wlo[idx4] = make_ushort4(bfh(v.x - bf2f(hx)), bfh(v.y - bf2f(hy)),
                                       bfh(v.z - bf2f(hz)), bfh(v.w - bf2f(hw)));
}

// ---------------------------------------------------------------------------
// Kernel 3/5: bf16x3 MFMA GEMM (validated core).  Epilogue change (QKV):
//   q rows -> fp32 qbuf [b][h][64][T]
//   k rows -> bf16 hi/lo K^T planes [b][h][T][64]  (conversion paid ONCE here
//             instead of 32x in attn)
//   v rows -> bf16 vbuf [b][h][64][T]
// ---------------------------------------------------------------------------
template <bool QKV>
__global__ __launch_bounds__(256) void gemm_t(
    const u16* __restrict__ Ahi, const u16* __restrict__ Alo,
    const u16* __restrict__ Whi_, const u16* __restrict__ Wlo_,
    const float* __restrict__ bias, const float* __restrict__ resid,
    float* __restrict__ outf, u16* __restrict__ outv,
    u16* __restrict__ outKhi, u16* __restrict__ outKlo) {
  __shared__ u16 At[2][4096];
  __shared__ u16 Bt[2][4096];
  int tid = threadIdx.x;
  int l = tid & 63, w = tid >> 6;
  int g = l >> 4, li = l & 15;
  int t0 = blockIdx.x * 128, m0 = blockIdx.y * 128, b = blockIdx.z;
  int wt = w & 1, wm = w >> 1;
  const u16* Abh = Ahi + ((size_t)b * TT + t0) * 512;
  const u16* Abl = Alo + ((size_t)b * TT + t0) * 512;
  const u16* Wbh = Whi_ + (size_t)m0 * 512;
  const u16* Wbl = Wlo_ + (size_t)m0 * 512;

  f32x4 dacc[4][4];
#pragma unroll
  for (int i = 0; i < 4; i++)
#pragma unroll
    for (int j = 0; j < 4; j++) dacc[i][j] = (f32x4){0.f, 0.f, 0.f, 0.f};

  for (int k0 = 0; k0 < 512; k0 += 32) {
    s16x8 rah[2], ral[2], rbh[2], rbl[2];
#pragma unroll
    for (int it = 0; it < 2; it++) {
      int gi = l + 64 * it;
      int rr = w * 32 + (gi >> 2);
      int k8 = gi & 3;
      size_t ga = (size_t)rr * 512 + k0 + k8 * 8;
      rah[it] = *(const s16x8*)&Abh[ga];
      ral[it] = *(const s16x8*)&Abl[ga];
      rbh[it] = *(const s16x8*)&Wbh[ga];
      rbl[it] = *(const s16x8*)&Wbl[ga];
    }
    __syncthreads();
#pragma unroll
    for (int it = 0; it < 2; it++) {
      int gi = l + 64 * it;
      int rr = w * 32 + (gi >> 2);
      int k8 = gi & 3;
      int u = rr * 4 + (k8 ^ ((rr >> 2) & 3));
      *(s16x8*)&At[0][u * 8] = rah[it];
      *(s16x8*)&At[1][u * 8] = ral[it];
      *(s16x8*)&Bt[0][u * 8] = rbh[it];
      *(s16x8*)&Bt[1][u * 8] = rbl[it];
    }
    __syncthreads();
    s16x8 bh[4], bl[4];
#pragma unroll
    for (int mb = 0; mb < 4; mb++) {
      int m = wm * 64 + mb * 16 + li;
      int u = m * 4 + (g ^ ((m >> 2) & 3));
      bh[mb] = *(const s16x8*)&Bt[0][u * 8];
      bl[mb] = *(const s16x8*)&Bt[1][u * 8];
    }
#pragma unroll
    for (int tb = 0; tb < 4; tb++) {
      int t = wt * 64 + tb * 16 + li;
      int u = t * 4 + (g ^ ((t >> 2) & 3));
      s16x8 ah = *(const s16x8*)&At[0][u * 8];
      s16x8 al = *(const s16x8*)&At[1][u * 8];
#pragma unroll
      for (int mb = 0; mb < 4; mb++) {
        dacc[tb][mb] = __builtin_amdgcn_mfma_f32_16x16x32_bf16(ah, bh[mb], dacc[tb][mb], 0, 0, 0);
        dacc[tb][mb] = __builtin_amdgcn_mfma_f32_16x16x32_bf16(ah, bl[mb], dacc[tb][mb], 0, 0, 0);
        dacc[tb][mb] = __builtin_amdgcn_mfma_f32_16x16x32_bf16(al, bh[mb], dacc[tb][mb], 0, 0, 0);
      }
    }
  }
#pragma unroll
  for (int tb = 0; tb < 4; tb++) {
    int t = t0 + wt * 64 + tb * 16 + 4 * g;
#pragma unroll
    for (int mb = 0; mb < 4; mb++) {
      int m = m0 + wm * 64 + mb * 16 + li;
      float bb = bias[m];
      f32x4 v = dacc[tb][mb];
      float rv[4] = {v[0] + bb, v[1] + bb, v[2] + bb, v[3] + bb};
      if (QKV) {
        int hh = m / 192, rr = m - hh * 192;   // uniform per fragment (16 | 64)
        if (rr < 64) {
          *(float4*)&outf[(((size_t)b * HEADS + hh) * 64 + rr) * TT + t] =
              make_float4(rv[0], rv[1], rv[2], rv[3]);
        } else if (rr < 128) {
          int c = rr - 64;
          size_t base = (((size_t)b * HEADS + hh) * TT + t) * 64 + c;
#pragma unroll
          for (int j = 0; j < 4; j++) {
            u16 h = bfh(rv[j]);
            outKhi[base + (size_t)j * 64] = h;
            outKlo[base + (size_t)j * 64] = bfh(rv[j] - bf2f(h));
          }
        } else {
          *(ushort4*)&outv[(((size_t)b * HEADS + hh) * 64 + (rr - 128)) * TT + t] =
              make_ushort4(bfh(rv[0]), bfh(rv[1]), bfh(rv[2]), bfh(rv[3]));
        }
      } else {
        size_t o = ((size_t)b * CC + m) * TT + t;
        float4 xv = *(const float4*)&resid[o];
        *(float4*)&outf[o] = make_float4(rv[0] + xv.x, rv[1] + xv.y,
                                         rv[2] + xv.z, rv[3] + xv.w);
      }
    }
  }
}

// ---------------------------------------------------------------------------
// Kernel 4: MFMA flash attention, widened: block = 128 q (4 waves x 32 q,
// each wave = 2 strips of 16).  K arrives pre-split/pre-transposed bf16
// (pure b128 copy staging); V pure copy; softmax in log2 domain (exp2);
// P packed via v_cvt_pk_bf16_f32.  Core MFMA structure = validated round-6/7.
// ---------------------------------------------------------------------------
__global__ __launch_bounds__(256, 2) void attn_kernel(
    const float* __restrict__ qbuf,  // [b][h][64][T] fp32
    const u16* __restrict__ khiT,    // [b][h][T][64] bf16 hi
    const u16* __restrict__ kloT,    // [b][h][T][64] bf16 lo
    const u16* __restrict__ vbuf,    // [b][h][64][T] bf16
    u16* __restrict__ athi, u16* __restrict__ atlo) {  // a^T planes [b][T][512]
  __shared__ u16 QhQl[16384];        // Qh[8192] | Ql[8192]; reused as Pe
  __shared__ u16 Kh[4096], Kl[4096];
  __shared__ u16 Vn[4096];
  __shared__ u16 Pb[8192];           // [128 q][64 s]

  u16* Qh = QhQl;
  u16* Ql = QhQl + 8192;

  int bh = blockIdx.y;
  int b = bh / HEADS, hh = bh % HEADS;
  int qt0 = blockIdx.x * 128;
  const float* qp = qbuf + (size_t)(b * HEADS + hh) * 64 * TT;
  const u16* khp = khiT + (size_t)(b * HEADS + hh) * TT * 64;
  const u16* klp = kloT + (size_t)(b * HEADS + hh) * TT * 64;
  const u16* vp = vbuf + (size_t)(b * HEADS + hh) * 64 * TT;

  int tid = threadIdx.x;
  int l = tid & 63, w = tid >> 6;
  int g = l >> 4, li = l & 15;
  int wq0 = w * 32;
  const float scale2 = 0.125f * 1.4426950408889634f;  // 1/sqrt(64) * log2(e)

  // ---- stage Q: 128 q x 64 c, transposed + hi/lo split, once ----
#pragma unroll
  for (int it = 0; it < 4; it++) {
    int ii = tid + it * 256;           // 0..1023
    int q4 = (ii & 31) * 4;            // 0..124
    int c2 = (ii >> 5) * 2;            // 0..62
    float4 fa = *(const float4*)&qp[(size_t)c2 * TT + qt0 + q4];
    float4 fb = *(const float4*)&qp[(size_t)(c2 + 1) * TT + qt0 + q4];
    float va[4] = {fa.x, fa.y, fa.z, fa.w};
    float vb[4] = {fb.x, fb.y, fb.z, fb.w};
#pragma unroll
    for (int j = 0; j < 4; j++) {
      float xa = va[j] * scale2, xb = vb[j] * scale2;
      u16 ha = bfh(xa), hbv = bfh(xb);
      u16 la = bfh(xa - bf2f(ha)), lb = bfh(xb - bf2f(hbv));
      int idx = swz(q4 + j, c2);
      *(ushort2*)&Qh[idx] = make_ushort2(ha, hbv);
      *(ushort2*)&Ql[idx] = make_ushort2(la, lb);
    }
  }
  __syncthreads();

  s16x8 qfh[2][2], qfl[2][2];          // [strip][ch]
#pragma unroll
  for (int st = 0; st < 2; st++) {
    int row = wq0 + st * 16 + li;
    qfh[st][0] = *(const s16x8*)&Qh[swz(row, g * 8)];
    qfh[st][1] = *(const s16x8*)&Qh[swz(row, 32 + g * 8)];
    qfl[st][0] = *(const s16x8*)&Ql[swz(row, g * 8)];
    qfl[st][1] = *(const s16x8*)&Ql[swz(row, 32 + g * 8)];
  }

  float m_run[2] = {-INFINITY, -INFINITY}, l_run[2] = {0.f, 0.f};
  f32x4 oacc[2][4];
#pragma unroll
  for (int st = 0; st < 2; st++)
#pragma unroll
    for (int i = 0; i < 4; i++) oacc[st][i] = (f32x4){0.f, 0.f, 0.f, 0.f};

  for (int s0 = 0; s0 < TT; s0 += 64) {
    __syncthreads();
    // ---- stage K: pure swizzled b128 copies (pre-converted by GEMM) ----
#pragma unroll
    for (int it = 0; it < 2; it++) {
      int mt = tid + it * 256;         // 0..511
      int s = mt >> 3, c8 = (mt & 7) * 8;
      size_t ga = (size_t)(s0 + s) * 64 + c8;
      *(s16x8*)&Kh[swz(s, c8)] = *(const s16x8*)&khp[ga];
      *(s16x8*)&Kl[swz(s, c8)] = *(const s16x8*)&klp[ga];
    }
    // ---- stage V: pure swizzled b128 copies ----
#pragma unroll
    for (int it = 0; it < 2; it++) {
      int mt = tid + it * 256;
      int c = mt >> 3, s8 = (mt & 7) * 8;
      *(s16x8*)&Vn[swz(c, s8)] = *(const s16x8*)&vp[(size_t)c * TT + s0 + s8];
    }
    __syncthreads();

#pragma unroll
    for (int st = 0; st < 2; st++) {
      // ---- QK^T (bf16x3): sacc[sf] = S^T rows sf*16..+15, col q ----
      f32x4 sacc[4];
#pragma unroll
      for (int sf = 0; sf < 4; sf++) sacc[sf] = (f32x4){0.f, 0.f, 0.f, 0.f};
#pragma unroll
      for (int sf = 0; sf < 4; sf++) {
        int row = sf * 16 + li;
#pragma unroll
        for (int ch = 0; ch < 2; ch++) {
          s16x8 kfh = *(const s16x8*)&Kh[swz(row, ch * 32 + g * 8)];
          s16x8 kfl = *(const s16x8*)&Kl[swz(row, ch * 32 + g * 8)];
          sacc[sf] = __builtin_amdgcn_mfma_f32_16x16x32_bf16(kfh, qfh[st][ch], sacc[sf], 0, 0, 0);
          sacc[sf] = __builtin_amdgcn_mfma_f32_16x16x32_bf16(kfh, qfl[st][ch], sacc[sf], 0, 0, 0);
          sacc[sf] = __builtin_amdgcn_mfma_f32_16x16x32_bf16(kfl, qfh[st][ch], sacc[sf], 0, 0, 0);
        }
      }

      // ---- online softmax (log2 domain), in registers ----
      float tmax = sacc[0][0];
#pragma unroll
      for (int sf = 0; sf < 4; sf++)
#pragma unroll
        for (int r = 0; r < 4; r++) tmax = fmaxf(tmax, sacc[sf][r]);
      tmax = fmaxf(tmax, __shfl_xor(tmax, 16));
      tmax = fmaxf(tmax, __shfl_xor(tmax, 32));
      float Mn = fmaxf(m_run[st], tmax);
      float corr = exp2f(m_run[st] - Mn);
      m_run[st] = Mn;
      float psum = 0.f;
      int prow = wq0 + st * 16 + li;
#pragma unroll
      for (int sf = 0; sf < 4; sf++) {
        float p0 = exp2f(sacc[sf][0] - Mn), p1 = exp2f(sacc[sf][1] - Mn);
        float p2 = exp2f(sacc[sf][2] - Mn), p3 = exp2f(sacc[sf][3] - Mn);
        psum += (p0 + p1) + (p2 + p3);
        u32 pk01, pk23;
        asm("v_cvt_pk_bf16_f32 %0, %1, %2" : "=v"(pk01) : "v"(p0), "v"(p1));
        asm("v_cvt_pk_bf16_f32 %0, %1, %2" : "=v"(pk23) : "v"(p2), "v"(p3));
        *(uint2*)&Pb[swz(prow, sf * 16 + g * 4)] = make_uint2(pk01, pk23);
      }
      psum += __shfl_xor(psum, 16);
      psum += __shfl_xor(psum, 32);
      l_run[st] = l_run[st] * corr + psum;

      float c0 = __shfl(corr, 4 * g + 0), c1 = __shfl(corr, 4 * g + 1);
      float c2v = __shfl(corr, 4 * g + 2), c3 = __shfl(corr, 4 * g + 3);

      // ---- PV ----
      s16x8 pa0 = *(const s16x8*)&Pb[swz(prow, g * 8)];
      s16x8 pa1 = *(const s16x8*)&Pb[swz(prow, 32 + g * 8)];
#pragma unroll
      for (int cf = 0; cf < 4; cf++) {
        f32x4 o = oacc[st][cf];
        o[0] *= c0; o[1] *= c1; o[2] *= c2v; o[3] *= c3;
        s16x8 vb0 = *(const s16x8*)&Vn[swz(cf * 16 + li, g * 8)];
        s16x8 vb1 = *(const s16x8*)&Vn[swz(cf * 16 + li, 32 + g * 8)];
        o = __builtin_amdgcn_mfma_f32_16x16x32_bf16(pa0, vb0, o, 0, 0, 0);
        o = __builtin_amdgcn_mfma_f32_16x16x32_bf16(pa1, vb1, o, 0, 0, 0);
        oacc[st][cf] = o;
      }
    }
  }

  // ---- epilogue: normalize, split hi/lo, write a^T planes via LDS bounce ----
  u16 uh[2][4][4], ul[2][4][4];
#pragma unroll
  for (int st = 0; st < 2; st++) {
    float i0 = 1.f / __shfl(l_run[st], 4 * g + 0);
    float i1 = 1.f / __shfl(l_run[st], 4 * g + 1);
    float i2 = 1.f / __shfl(l_run[st], 4 * g + 2);
    float i3 = 1.f / __shfl(l_run[st], 4 * g + 3);
    float ir[4] = {i0, i1, i2, i3};
#pragma unroll
    for (int cf = 0; cf < 4; cf++)
#pragma unroll
      for (int r = 0; r < 4; r++) {
        float v = oacc[st][cf][r] * ir[r];
        uh[st][cf][r] = bfh(v);
        ul[st][cf][r] = bfh(v - bf2f(uh[st][cf][r]));
      }
  }
  u16* Pe = QhQl;                      // 128 x 72 = 9216 u16 <= 16384
#pragma unroll
  for (int plane = 0; plane < 2; plane++) {
    __syncthreads();
#pragma unroll
    for (int st = 0; st < 2; st++)
#pragma unroll
      for (int cf = 0; cf < 4; cf++)
#pragma unroll
        for (int r = 0; r < 4; r++)
          Pe[(wq0 + st * 16 + 4 * g + r) * 72 + cf * 16 + li] =
              plane ? ul[st][cf][r] : uh[st][cf][r];
    __syncthreads();
    int q = tid >> 1, c0r = (tid & 1) * 32;
    u16* dst = (plane ? atlo : athi) + ((size_t)b * TT + qt0 + q) * CC + hh * 64 + c0r;
    const u16* src = &Pe[q * 72 + c0r];
    *(s16x8*)&dst[0] = *(const s16x8*)&src[0];
    *(s16x8*)&dst[8] = *(const s16x8*)&src[8];
    *(s16x8*)&dst[16] = *(const s16x8*)&src[16];
    *(s16x8*)&dst[24] = *(const s16x8*)&src[24];
  }
}

// ---------------------------------------------------------------------------
extern "C" void kernel_launch(void* const* d_in, const int* in_sizes, int n_in,
                              void* d_out, int out_size, void* d_ws, size_t ws_size,
                              hipStream_t stream) {
  (void)in_sizes; (void)n_in; (void)out_size; (void)ws_size;
  const float* x      = (const float*)d_in[0];
  const float* norm_w = (const float*)d_in[1];
  const float* norm_b = (const float*)d_in[2];
  const float* qkv_w  = (const float*)d_in[3];
  const float* qkv_b  = (const float*)d_in[4];
  const float* proj_w = (const float*)d_in[5];
  const float* proj_b = (const float*)d_in[6];
  float* out = (float*)d_out;
  char* wsb = (char*)d_ws;

  // ws layout (bytes), total ~60 MB < 64 MiB:
  u16* hthi   = (u16*)(wsb);                    //  8 MB  h^T hi (later a^T hi)
  u16* htlo   = (u16*)(wsb + 8388608);          //  8 MB  h^T lo (later a^T lo)
  float* qbuf = (float*)(wsb + 16777216);       // 16 MB  q fp32 [b][h][64][T]
  u16* khiT   = (u16*)(wsb + 33554432);         //  8 MB  K^T hi [b][h][T][64]
  u16* kloT   = (u16*)(wsb + 41943040);         //  8 MB  K^T lo
  u16* vbuf   = (u16*)(wsb + 50331648);         //  8 MB  v bf16 [b][h][64][T]
  u16* whi    = (u16*)(wsb + 58720256);         //  2 MB
  u16* wlo    = (u16*)(wsb + 60817408);         //  2 MB
  float2* stats = (float2*)(wsb + 62914560);    //  1 KB

  gn_stats<<<BB * GG, 256, 0, stream>>>(x, stats);
  gn_norm_t<<<dim3(64, BB), 256, 0, stream>>>(x, norm_w, norm_b, stats, hthi, htlo);
  wconv<<<1024, 256, 0, stream>>>(qkv_w, proj_w, whi, wlo);
  gemm_t<true><<<dim3(16, 12, BB), 256, 0, stream>>>(
      hthi, htlo, whi, wlo, qkv_b, nullptr, qbuf, vbuf, khiT, kloT);
  attn_kernel<<<dim3(TT / 128, BB * HEADS), 256, 0, stream>>>(
      qbuf, khiT, kloT, vbuf, hthi, htlo);
  gemm_t<false><<<dim3(16, 4, BB), 256, 0, stream>>>(
      hthi, htlo, whi + 786432, wlo + 786432, proj_b, x, out, nullptr, nullptr, nullptr);
}